// Round 2
// baseline (1928.978 us; speedup 1.0000x reference)
//
#include <hip/hip_runtime.h>
#include <hip/hip_bf16.h>

typedef __hip_bfloat16 bf16;

#define N_NODES 50000
#define N_EDGES 1600000
#define FIN 8
#define HD 64
#define NH (N_NODES * HD)
#define NLAYERS 3

__device__ __forceinline__ float b2f(bf16 v) { return __bfloat162float(v); }

// ---------------- dtype detection ----------------
// edge_weight ~ Uniform(0,1). If the buffer really holds bf16, every bf16-view
// value is in [0,1]. If it holds float32, the low-half bf16 views have random
// exponent bits -> out of range / NaN. flag: 0 = inputs bf16, 1 = inputs f32.
__global__ void k_detect(const void* __restrict__ ew, int* __restrict__ flag) {
    int ok = 1;
    for (int i = threadIdx.x; i < 512; i += 64) {
        float v = b2f(((const bf16*)ew)[i]);
        if (!(v >= 0.f && v <= 1.f)) ok = 0;
    }
    unsigned long long m = __ballot(ok);
    if (threadIdx.x == 0) *flag = (m == 0xFFFFFFFFFFFFFFFFull) ? 0 : 1;
}

__global__ void k_convert(const void* __restrict__ src, float* __restrict__ dst,
                          int n, const int* __restrict__ flag) {
    int i = blockIdx.x * 256 + threadIdx.x;
    if (i >= n) return;
    if (*flag) dst[i] = ((const float*)src)[i];
    else       dst[i] = b2f(((const bf16*)src)[i]);
}

// ---------------- setup: degree, norm, CSR ----------------

__global__ void k_degree(const int* __restrict__ col, const float* __restrict__ w,
                         float* __restrict__ deg) {
    int e = blockIdx.x * 256 + threadIdx.x;
    if (e < N_EDGES) atomicAdd(&deg[col[e]], w[e]);
}

__global__ void k_dis(float* __restrict__ deg) {
    int i = blockIdx.x * 256 + threadIdx.x;
    if (i < N_NODES) {
        float d = deg[i];
        deg[i] = (d > 0.f) ? fminf(1.f / sqrtf(d), 1e6f) : 1e6f;
    }
}

__global__ void k_count(const int* __restrict__ row, int* __restrict__ cnt) {
    int e = blockIdx.x * 256 + threadIdx.x;
    if (e < N_EDGES) atomicAdd(&cnt[row[e]], 1);
}

// single-block sequential-chunk Hillis-Steele scan over 50001 entries
__global__ void k_scan(const int* __restrict__ cnt, int* __restrict__ row_ptr) {
    __shared__ int sm[1024];
    __shared__ int carry;
    if (threadIdx.x == 0) carry = 0;
    __syncthreads();
    for (int base = 0; base < N_NODES; base += 1024) {
        int i = base + threadIdx.x;
        int v = (i < N_NODES) ? cnt[i] : 0;
        sm[threadIdx.x] = v;
        __syncthreads();
        for (int off = 1; off < 1024; off <<= 1) {
            int t = 0;
            if (threadIdx.x >= off) t = sm[threadIdx.x - off];
            __syncthreads();
            if (threadIdx.x >= off) sm[threadIdx.x] += t;
            __syncthreads();
        }
        if (i < N_NODES) row_ptr[i] = carry + sm[threadIdx.x] - v;  // exclusive
        __syncthreads();
        if (threadIdx.x == 0) carry += sm[1023];
        __syncthreads();
    }
    if (threadIdx.x == 0) row_ptr[N_NODES] = N_EDGES;
}

__global__ void k_fill(const int* __restrict__ ei, const float* __restrict__ w,
                       const float* __restrict__ dis,
                       const int* __restrict__ row_ptr, int* __restrict__ fill,
                       int* __restrict__ csr_col, float* __restrict__ csr_norm) {
    int e = blockIdx.x * 256 + threadIdx.x;
    if (e < N_EDGES) {
        int r = ei[e], c = ei[N_EDGES + e];
        int pos = row_ptr[r] + atomicAdd(&fill[r], 1);
        csr_col[pos] = c;
        csr_norm[pos] = dis[r] * w[e] * dis[c];
    }
}

// ---------------- input projection h = x @ W_in^T + b ----------------

__global__ void k_inproj(const float* __restrict__ x, const float* __restrict__ W,
                         const float* __restrict__ b, float* __restrict__ h) {
    __shared__ float Wt[FIN * HD];  // Wt[j*64+f]
    __shared__ float bs[HD];
    int t = threadIdx.x;
    for (int idx = t; idx < FIN * HD; idx += 256) {
        int f = idx >> 3, j = idx & 7;
        Wt[j * 64 + f] = W[idx];
    }
    if (t < 64) bs[t] = b[t];
    __syncthreads();
    int gid = blockIdx.x * 256 + t;
    if (gid < NH) {
        int i = gid >> 6, f = gid & 63;
        const float* xr = x + i * FIN;
        float acc = bs[f];
#pragma unroll
        for (int j = 0; j < FIN; ++j) acc += xr[j] * Wt[j * 64 + f];
        h[gid] = acc;
    }
}

// ---------------- per-layer stats + coefficient MLP ----------------

__global__ void k_stats(const float* __restrict__ h, float* __restrict__ stats) {
    __shared__ float ssum[256], ssq[256];
    int t = threadIdx.x;
    float ls = 0.f, lq = 0.f;
    // stride 102400 % 64 == 0 -> each thread's feature index is constant
    for (int idx = blockIdx.x * 256 + t; idx < NH; idx += 102400) {
        float v = h[idx];
        ls += v; lq += v * v;
    }
    ssum[t] = ls; ssq[t] = lq;
    __syncthreads();
    if (t < 64) {
        float a = ssum[t] + ssum[t + 64] + ssum[t + 128] + ssum[t + 192];
        atomicAdd(&stats[t], a);  // per-feature sum
        float q = ssq[t] + ssq[t + 64] + ssq[t + 128] + ssq[t + 192];
        for (int off = 32; off; off >>= 1) q += __shfl_down(q, off, 64);
        if (t == 0) atomicAdd(&stats[64], q);  // total sum of squares
    }
}

__global__ void k_coeffs(const float* __restrict__ stats,
                         const float* __restrict__ W1, const float* __restrict__ b1,
                         const float* __restrict__ W2, const float* __restrict__ b2,
                         int layer, float* __restrict__ coeffs) {
    __shared__ float ci[68];
    __shared__ float hid[32];
    __shared__ float lg[6];
    int t = threadIdx.x;  // blockDim = 64
    float sf = stats[t];
    float tot = sf;
    for (int off = 1; off < 64; off <<= 1) tot += __shfl_xor(tot, off, 64);
    ci[t] = sf / (float)N_NODES;  // x_mean[f]
    if (t == 0) {
        float sumsq = stats[64];
        float mean = tot / (float)NH;
        float var = (sumsq - (float)NH * mean * mean) / (float)(NH - 1);  // ddof=1
        ci[64] = mean;
        ci[65] = sqrtf(fmaxf(var, 0.f));
        ci[66] = (float)N_NODES;
        ci[67] = (float)N_EDGES;
    }
    __syncthreads();
    if (t < 32) {
        float a = b1[layer * 32 + t];
        const float* wr = W1 + (layer * 32 + t) * 68;
        for (int j = 0; j < 68; ++j) a += ci[j] * wr[j];
        hid[t] = fmaxf(a, 0.f);
    }
    __syncthreads();
    if (t < 6) {
        float a = b2[layer * 6 + t];
        const float* wr = W2 + (layer * 6 + t) * 32;
        for (int g = 0; g < 32; ++g) a += hid[g] * wr[g];
        lg[t] = a;
    }
    __syncthreads();
    if (t == 0) {
        float mx = lg[0];
        for (int p = 1; p < 6; ++p) mx = fmaxf(mx, lg[p]);
        float s = 0.f, e[6];
        for (int p = 0; p < 6; ++p) { e[p] = expf(lg[p] - mx); s += e[p]; }
        for (int p = 0; p < 6; ++p) coeffs[p] = e[p] / s;
    }
}

// ---------------- diffusion SpMM: one wave per node, lane = feature ----------------

__global__ void __launch_bounds__(256) k_spmm(
    const float* __restrict__ txo, float* __restrict__ txn,
    float* __restrict__ result, const float* __restrict__ h,
    const int* __restrict__ row_ptr, const int* __restrict__ csr_col,
    const float* __restrict__ csr_norm, const float* __restrict__ coeffs, int k) {
    int wv = (blockIdx.x * 256 + threadIdx.x) >> 6;
    int lane = threadIdx.x & 63;
    if (wv >= N_NODES) return;
    int s = row_ptr[wv], e = row_ptr[wv + 1];
    float acc = 0.f;
    int j = s;
    for (; j + 3 < e; j += 4) {
        int c0 = csr_col[j], c1 = csr_col[j + 1], c2 = csr_col[j + 2], c3 = csr_col[j + 3];
        float n0 = csr_norm[j], n1 = csr_norm[j + 1], n2 = csr_norm[j + 2], n3 = csr_norm[j + 3];
        acc += n0 * txo[c0 * 64 + lane] + n1 * txo[c1 * 64 + lane] +
               n2 * txo[c2 * 64 + lane] + n3 * txo[c3 * 64 + lane];
    }
    for (; j < e; ++j) acc += csr_norm[j] * txo[csr_col[j] * 64 + lane];
    int o = wv * 64 + lane;
    txn[o] = acc;
    if (k == 1) result[o] = coeffs[0] * h[o] + coeffs[1] * acc;
    else        result[o] += coeffs[k] * acc;
}

// ---------------- layernorm(h + result) ----------------

__global__ void k_layernorm(float* __restrict__ h, const float* __restrict__ result,
                            const float* __restrict__ sc, const float* __restrict__ bi,
                            int layer, int last, void* __restrict__ outv,
                            const int* __restrict__ flag) {
    int wv = (blockIdx.x * 256 + threadIdx.x) >> 6;
    int lane = threadIdx.x & 63;
    if (wv >= N_NODES) return;
    int o = wv * 64 + lane;
    float v = h[o] + result[o];
    float m = v;
    for (int off = 1; off < 64; off <<= 1) m += __shfl_xor(m, off, 64);
    m *= (1.f / 64.f);
    float d = v - m;
    float q = d * d;
    for (int off = 1; off < 64; off <<= 1) q += __shfl_xor(q, off, 64);
    float var = q * (1.f / 64.f);  // ddof=0
    float y = d / sqrtf(var + 1e-5f) * sc[layer * 64 + lane] + bi[layer * 64 + lane];
    h[o] = y;
    if (last) {
        if (*flag) ((float*)outv)[N_EDGES + o] = y;
        else       ((bf16*)outv)[N_EDGES + o] = __float2bfloat16(y);
    }
}

// ---------------- edge predictor ----------------
// u = W1[:, :64] @ h_i, v = W1[:, 64:] @ h_i per node
__global__ void __launch_bounds__(256) k_uv(const float* __restrict__ h,
                                            const float* __restrict__ W1,
                                            float* __restrict__ u, float* __restrict__ v) {
    __shared__ float Wt[128 * 65];  // Wt[j*65+f], padded stride kills bank conflicts
    __shared__ float hs[4 * 64];
    int t = threadIdx.x;
    for (int idx = t; idx < 8192; idx += 256) {
        int f = idx >> 7, j = idx & 127;
        Wt[j * 65 + f] = W1[idx];
    }
    int node0 = blockIdx.x * 4;
    hs[t] = h[node0 * 64 + t];
    __syncthreads();
    int ni = t >> 6, f = t & 63;
    const float* hr = hs + ni * 64;
    float au = 0.f, av = 0.f;
#pragma unroll 8
    for (int j = 0; j < 64; ++j) {
        float xv = hr[j];
        au += Wt[j * 65 + f] * xv;
        av += Wt[(j + 64) * 65 + f] * xv;
    }
    int i = node0 + ni;
    u[i * 64 + f] = au;
    v[i * 64 + f] = av;
}

// 2 edges per wave: lanes' g<32 group -> edge A, g>=32 -> edge B.
// Loop trip count is exactly 80 for every wave -> __syncthreads is uniform.
__global__ void __launch_bounds__(256) k_edgepred(
    const float* __restrict__ u, const float* __restrict__ v,
    const int* __restrict__ ei, const float* __restrict__ eb1,
    const float* __restrict__ eW2, const float* __restrict__ eb2,
    const float* __restrict__ eW3, const float* __restrict__ eb3,
    void* __restrict__ outv, const int* __restrict__ flag) {
    __shared__ float W2t[64 * 33];  // W2t[j*33+g]
    __shared__ float b1s[64];
    __shared__ float W3s[32];
    __shared__ float b2s[32];
    __shared__ float b3s;
    __shared__ float e1s[4][2][64];
    int t = threadIdx.x;
    int f32o = *flag;
    for (int idx = t; idx < 2048; idx += 256) {
        int g = idx >> 6, j = idx & 63;
        W2t[j * 33 + g] = eW2[idx];
    }
    if (t < 64) b1s[t] = eb1[t];
    else if (t < 96) W3s[t - 64] = eW3[t - 64];
    else if (t < 128) b2s[t - 96] = eb2[t - 96];
    else if (t == 128) b3s = eb3[0];
    __syncthreads();
    int wid = t >> 6, lane = t & 63;
    int g = lane & 31, which = lane >> 5;
    int gw = blockIdx.x * 4 + wid;  // 10000 waves, 20000 edges/sweep, exactly 80 iters
    const int* rowp = ei;
    const int* colp = ei + N_EDGES;
    for (int base = gw * 2; base < N_EDGES; base += 20000) {
        int ra = rowp[base], ca = colp[base];
        int rb = rowp[base + 1], cb = colp[base + 1];
        float e1a = fmaxf(u[ra * 64 + lane] + v[ca * 64 + lane] + b1s[lane], 0.f);
        float e1b = fmaxf(u[rb * 64 + lane] + v[cb * 64 + lane] + b1s[lane], 0.f);
        e1s[wid][0][lane] = e1a;
        e1s[wid][1][lane] = e1b;
        __syncthreads();
        const float* ep = &e1s[wid][which][0];
        float acc = b2s[g];
#pragma unroll 8
        for (int j = 0; j < 64; ++j) acc += W2t[j * 33 + g] * ep[j];
        acc = fmaxf(acc, 0.f);
        float s = W3s[g] * acc;
        for (int off = 1; off < 32; off <<= 1) s += __shfl_xor(s, off, 64);
        if (g == 0) {
            float z = s + b3s;
            float p = 1.f / (1.f + __expf(-z));
            if (f32o) ((float*)outv)[base + which] = p;
            else      ((bf16*)outv)[base + which] = __float2bfloat16(p);
        }
        __syncthreads();
    }
}

// ---------------- launch ----------------

extern "C" void kernel_launch(void* const* d_in, const int* in_sizes, int n_in,
                              void* d_out, int out_size, void* d_ws, size_t ws_size,
                              hipStream_t stream) {
    (void)in_sizes; (void)n_in; (void)out_size; (void)ws_size;
    const void* x_r    = d_in[0];
    const int*  ei     = (const int*)d_in[1];
    const void* ew_r   = d_in[2];
    const void* Win_r  = d_in[3];
    const void* bin_r  = d_in[4];
    const void* cW1_r  = d_in[5];
    const void* cb1_r  = d_in[6];
    const void* cW2_r  = d_in[7];
    const void* cb2_r  = d_in[8];
    const void* lns_r  = d_in[9];
    const void* lnb_r  = d_in[10];
    const void* eW1_r  = d_in[11];
    const void* eb1_r  = d_in[12];
    const void* eW2_r  = d_in[13];
    const void* eb2_r  = d_in[14];
    const void* eW3_r  = d_in[15];
    const void* eb3_r  = d_in[16];

    char* w = (char*)d_ws;
    float* h       = (float*)w; w += (size_t)NH * 4;        // 12.8 MB
    float* txA     = (float*)w; w += (size_t)NH * 4;
    float* txB     = (float*)w; w += (size_t)NH * 4;
    float* result  = (float*)w; w += (size_t)NH * 4;
    float* csr_nm  = (float*)w; w += (size_t)N_EDGES * 4;
    int*   csr_c   = (int*)w;   w += (size_t)N_EDGES * 4;
    int*   row_ptr = (int*)w;   w += 200192;
    // converted small weights (~72 KB)
    float* cWin  = (float*)w; w += 2048;
    float* cbin  = (float*)w; w += 256;
    float* ccW1  = (float*)w; w += 26112;
    float* ccb1  = (float*)w; w += 384;
    float* ccW2  = (float*)w; w += 2304;
    float* ccb2  = (float*)w; w += 128;
    float* clns  = (float*)w; w += 768;
    float* clnb  = (float*)w; w += 768;
    float* ceW1  = (float*)w; w += 32768;
    float* ceb1  = (float*)w; w += 256;
    float* ceW2  = (float*)w; w += 8192;
    float* ceb2  = (float*)w; w += 128;
    float* ceW3  = (float*)w; w += 128;
    float* ceb3  = (float*)w; w += 128;
    char* zero_base = w;
    float* deg     = (float*)w; w += 200192;
    int*   cnt     = (int*)w;   w += 200192;
    int*   fill    = (int*)w;   w += 200192;
    float* stats   = (float*)w; w += 1024;                  // 3 layers x 80
    size_t zero_bytes = (size_t)(w - zero_base);
    float* coeffs  = (float*)w; w += 128;                   // 3 layers x 8
    int*   flag    = (int*)w;   w += 128;

    // big converted inputs live inside txA (dead before txA's first write at layer0 k=1)
    float* cx  = txA;            // 400000 floats
    float* cew = txA + 400000;   // 1600000 floats

    hipMemsetAsync(zero_base, 0, zero_bytes, stream);

    k_detect<<<1, 64, 0, stream>>>(ew_r, flag);
    k_convert<<<1563, 256, 0, stream>>>(x_r,   cx,   N_NODES * FIN, flag);
    k_convert<<<6250, 256, 0, stream>>>(ew_r,  cew,  N_EDGES, flag);
    k_convert<<<2, 256, 0, stream>>>(Win_r, cWin, 512, flag);
    k_convert<<<1, 256, 0, stream>>>(bin_r, cbin, 64, flag);
    k_convert<<<26, 256, 0, stream>>>(cW1_r, ccW1, NLAYERS * 32 * 68, flag);
    k_convert<<<1, 256, 0, stream>>>(cb1_r, ccb1, NLAYERS * 32, flag);
    k_convert<<<3, 256, 0, stream>>>(cW2_r, ccW2, NLAYERS * 6 * 32, flag);
    k_convert<<<1, 256, 0, stream>>>(cb2_r, ccb2, NLAYERS * 6, flag);
    k_convert<<<1, 256, 0, stream>>>(lns_r, clns, NLAYERS * 64, flag);
    k_convert<<<1, 256, 0, stream>>>(lnb_r, clnb, NLAYERS * 64, flag);
    k_convert<<<32, 256, 0, stream>>>(eW1_r, ceW1, 64 * 128, flag);
    k_convert<<<1, 256, 0, stream>>>(eb1_r, ceb1, 64, flag);
    k_convert<<<8, 256, 0, stream>>>(eW2_r, ceW2, 32 * 64, flag);
    k_convert<<<1, 256, 0, stream>>>(eb2_r, ceb2, 32, flag);
    k_convert<<<1, 256, 0, stream>>>(eW3_r, ceW3, 32, flag);
    k_convert<<<1, 256, 0, stream>>>(eb3_r, ceb3, 1, flag);

    k_degree<<<6250, 256, 0, stream>>>(ei + N_EDGES, cew, deg);
    k_dis<<<196, 256, 0, stream>>>(deg);
    k_count<<<6250, 256, 0, stream>>>(ei, cnt);
    k_scan<<<1, 1024, 0, stream>>>(cnt, row_ptr);
    k_fill<<<6250, 256, 0, stream>>>(ei, cew, deg, row_ptr, fill, csr_c, csr_nm);
    k_inproj<<<12500, 256, 0, stream>>>(cx, cWin, cbin, h);

    for (int l = 0; l < NLAYERS; ++l) {
        k_stats<<<400, 256, 0, stream>>>(h, stats + l * 80);
        k_coeffs<<<1, 64, 0, stream>>>(stats + l * 80, ccW1, ccb1, ccW2, ccb2, l,
                                       coeffs + l * 8);
        const float* to = h;
        float* tn = txA;
        for (int k = 1; k <= 5; ++k) {
            k_spmm<<<12500, 256, 0, stream>>>(to, tn, result, h, row_ptr, csr_c, csr_nm,
                                              coeffs + l * 8, k);
            to = tn;
            tn = (tn == txA) ? txB : txA;
        }
        k_layernorm<<<12500, 256, 0, stream>>>(h, result, clns, clnb, l,
                                               (l == NLAYERS - 1) ? 1 : 0, d_out, flag);
    }

    k_uv<<<12500, 256, 0, stream>>>(h, ceW1, txA, txB);
    k_edgepred<<<2500, 256, 0, stream>>>(txA, txB, ei, ceb1, ceW2, ceb2, ceW3, ceb3,
                                         d_out, flag);
}

// Round 3
// 1528.020 us; speedup vs baseline: 1.2624x; 1.2624x over previous
//
#include <hip/hip_runtime.h>
#include <hip/hip_bf16.h>

typedef __hip_bfloat16 bf16;
typedef __attribute__((ext_vector_type(8))) short short8;
typedef __attribute__((ext_vector_type(4))) float f32x4;

#define N_NODES 50000
#define N_EDGES 1600000
#define FIN 8
#define HD 64
#define NH (N_NODES * HD)
#define NLAYERS 3

__device__ __forceinline__ float b2f(bf16 v) { return __bfloat162float(v); }
__device__ __forceinline__ float bu2f(unsigned int u) { return __uint_as_float(u << 16); }
__device__ __forceinline__ unsigned short f2bu(float f) {
    unsigned int x = __float_as_uint(f);
    unsigned int r = x + 0x7FFFu + ((x >> 16) & 1u);
    return (unsigned short)(r >> 16);
}

// ---------------- dtype detection ----------------
__global__ void k_detect(const void* __restrict__ ew, int* __restrict__ flag) {
    int ok = 1;
    for (int i = threadIdx.x; i < 512; i += 64) {
        float v = b2f(((const bf16*)ew)[i]);
        if (!(v >= 0.f && v <= 1.f)) ok = 0;
    }
    unsigned long long m = __ballot(ok);
    if (threadIdx.x == 0) *flag = (m == 0xFFFFFFFFFFFFFFFFull) ? 0 : 1;
}

// big converts: x (400000) then ew (1600000)
__global__ void k_conv_big(const void* __restrict__ xs, const void* __restrict__ es,
                           float* __restrict__ cx, float* __restrict__ cew,
                           const int* __restrict__ flag) {
    int idx = blockIdx.x * 256 + threadIdx.x;
    int f32 = *flag;
    if (idx < 400000) {
        cx[idx] = f32 ? ((const float*)xs)[idx] : bu2f(((const unsigned short*)xs)[idx]);
    } else if (idx < 2000000) {
        int o = idx - 400000;
        cew[o] = f32 ? ((const float*)es)[o] : bu2f(((const unsigned short*)es)[o]);
    }
}

struct ConvArgs {
    const void* src[14];
    float* dst[14];
    int cum[15];
};

__global__ void k_conv_small(ConvArgs a, const int* __restrict__ flag) {
    int idx = blockIdx.x * 256 + threadIdx.x;
    if (idx >= a.cum[14]) return;
    int s = 0;
    while (idx >= a.cum[s + 1]) ++s;
    int off = idx - a.cum[s];
    if (*flag) a.dst[s][off] = ((const float*)a.src[s])[off];
    else       a.dst[s][off] = bu2f(((const unsigned short*)a.src[s])[off]);
}

// ---------------- setup: degree+count, dis, scan, fill ----------------

__global__ void k_setup(const int* __restrict__ ei, const float* __restrict__ w,
                        float* __restrict__ deg, int* __restrict__ cnt) {
    int e = blockIdx.x * 256 + threadIdx.x;
    if (e < N_EDGES) {
        atomicAdd(&deg[ei[N_EDGES + e]], w[e]);
        atomicAdd(&cnt[ei[e]], 1);
    }
}

__global__ void k_dis(float* __restrict__ deg) {
    int i = blockIdx.x * 256 + threadIdx.x;
    if (i < N_NODES) {
        float d = deg[i];
        deg[i] = (d > 0.f) ? fminf(1.f / sqrtf(d), 1e6f) : 1e6f;
    }
}

// 2-pass scan: per-thread chunk of 49, one 1024-wide Hillis-Steele
__global__ void k_scan(const int* __restrict__ cnt, int* __restrict__ row_ptr) {
    __shared__ int part[1024];
    int t = threadIdx.x;
    const int CH = 49;  // 1024*49 = 50176 >= 50001
    int base = t * CH;
    int s = 0;
    for (int i = 0; i < CH; ++i) {
        int idx = base + i;
        if (idx < N_NODES) s += cnt[idx];
    }
    part[t] = s;
    __syncthreads();
    int val = s;
    for (int off = 1; off < 1024; off <<= 1) {
        int other = (t >= off) ? part[t - off] : 0;
        __syncthreads();
        val += other;
        part[t] = val;
        __syncthreads();
    }
    int run = val - s;  // exclusive prefix at chunk start
    for (int i = 0; i < CH; ++i) {
        int idx = base + i;
        if (idx <= N_NODES) row_ptr[idx] = run;
        if (idx < N_NODES) run += cnt[idx];
    }
}

// pairs[pos] = {col, bits(norm)} in CSR order
__global__ void k_fill(const int* __restrict__ ei, const float* __restrict__ w,
                       const float* __restrict__ dis,
                       const int* __restrict__ row_ptr, int* __restrict__ fill,
                       int2* __restrict__ pairs) {
    int e = blockIdx.x * 256 + threadIdx.x;
    if (e < N_EDGES) {
        int r = ei[e], c = ei[N_EDGES + e];
        int pos = row_ptr[r] + atomicAdd(&fill[r], 1);
        int2 p;
        p.x = c;
        p.y = __float_as_int(dis[r] * w[e] * dis[c]);
        pairs[pos] = p;
    }
}

// late CSR grouping for edge predictor: meta[pos] = {col,row,eid,0}
__global__ void k_fill2(const int* __restrict__ ei, const int* __restrict__ row_ptr,
                        int* __restrict__ fill2, int4* __restrict__ meta) {
    int e = blockIdx.x * 256 + threadIdx.x;
    if (e < N_EDGES) {
        int r = ei[e], c = ei[N_EDGES + e];
        int pos = row_ptr[r] + atomicAdd(&fill2[r], 1);
        int4 m;
        m.x = c; m.y = r; m.z = e; m.w = 0;
        meta[pos] = m;
    }
}

// ---------------- input projection ----------------

__global__ void k_inproj(const float* __restrict__ x, const float* __restrict__ W,
                         const float* __restrict__ b, float* __restrict__ h,
                         unsigned short* __restrict__ h_bf) {
    __shared__ float Wt[FIN * HD];
    __shared__ float bs[HD];
    int t = threadIdx.x;
    for (int idx = t; idx < FIN * HD; idx += 256) {
        int f = idx >> 3, j = idx & 7;
        Wt[j * 64 + f] = W[idx];
    }
    if (t < 64) bs[t] = b[t];
    __syncthreads();
    int gid = blockIdx.x * 256 + t;
    if (gid < NH) {
        int i = gid >> 6, f = gid & 63;
        const float* xr = x + i * FIN;
        float acc = bs[f];
#pragma unroll
        for (int j = 0; j < FIN; ++j) acc += xr[j] * Wt[j * 64 + f];
        h[gid] = acc;
        h_bf[gid] = f2bu(acc);
    }
}

// ---------------- stats + coefficient MLP ----------------

__global__ void k_stats(const float* __restrict__ h, float* __restrict__ stats) {
    __shared__ float ssum[256], ssq[256];
    int t = threadIdx.x;
    float ls = 0.f, lq = 0.f;
    for (int idx = blockIdx.x * 256 + t; idx < NH; idx += 102400) {
        float v = h[idx];
        ls += v; lq += v * v;
    }
    ssum[t] = ls; ssq[t] = lq;
    __syncthreads();
    if (t < 64) {
        float a = ssum[t] + ssum[t + 64] + ssum[t + 128] + ssum[t + 192];
        atomicAdd(&stats[t], a);
        float q = ssq[t] + ssq[t + 64] + ssq[t + 128] + ssq[t + 192];
        for (int off = 32; off; off >>= 1) q += __shfl_down(q, off, 64);
        if (t == 0) atomicAdd(&stats[64], q);
    }
}

__global__ void k_coeffs(const float* __restrict__ stats,
                         const float* __restrict__ W1, const float* __restrict__ b1,
                         const float* __restrict__ W2, const float* __restrict__ b2,
                         int layer, float* __restrict__ coeffs) {
    __shared__ float ci[68];
    __shared__ float hid[32];
    __shared__ float lg[6];
    int t = threadIdx.x;
    float sf = stats[t];
    float tot = sf;
    for (int off = 1; off < 64; off <<= 1) tot += __shfl_xor(tot, off, 64);
    ci[t] = sf / (float)N_NODES;
    if (t == 0) {
        float sumsq = stats[64];
        float mean = tot / (float)NH;
        float var = (sumsq - (float)NH * mean * mean) / (float)(NH - 1);
        ci[64] = mean;
        ci[65] = sqrtf(fmaxf(var, 0.f));
        ci[66] = (float)N_NODES;
        ci[67] = (float)N_EDGES;
    }
    __syncthreads();
    if (t < 32) {
        float a = b1[layer * 32 + t];
        const float* wr = W1 + (layer * 32 + t) * 68;
        for (int j = 0; j < 68; ++j) a += ci[j] * wr[j];
        hid[t] = fmaxf(a, 0.f);
    }
    __syncthreads();
    if (t < 6) {
        float a = b2[layer * 6 + t];
        const float* wr = W2 + (layer * 6 + t) * 32;
        for (int g = 0; g < 32; ++g) a += hid[g] * wr[g];
        lg[t] = a;
    }
    __syncthreads();
    if (t == 0) {
        float mx = lg[0];
        for (int p = 1; p < 6; ++p) mx = fmaxf(mx, lg[p]);
        float s = 0.f, e[6];
        for (int p = 0; p < 6; ++p) { e[p] = expf(lg[p] - mx); s += e[p]; }
        for (int p = 0; p < 6; ++p) coeffs[p] = e[p] / s;
    }
}

// ---------------- SpMM hop: bf16 rows, wave per node ----------------

__global__ void __launch_bounds__(256) k_spmm(
    const unsigned short* __restrict__ txo, unsigned short* __restrict__ txn,
    const int* __restrict__ row_ptr, const int2* __restrict__ pairs) {
    int wv = (blockIdx.x * 256 + threadIdx.x) >> 6;
    int lane = threadIdx.x & 63;
    if (wv >= N_NODES) return;
    int s = row_ptr[wv], e = row_ptr[wv + 1];
    float acc = 0.f;
    int j = s;
    for (; j + 7 < e; j += 8) {
        int2 p0 = pairs[j],     p1 = pairs[j + 1], p2 = pairs[j + 2], p3 = pairs[j + 3];
        int2 p4 = pairs[j + 4], p5 = pairs[j + 5], p6 = pairs[j + 6], p7 = pairs[j + 7];
        float g0 = bu2f(txo[p0.x * 64 + lane]);
        float g1 = bu2f(txo[p1.x * 64 + lane]);
        float g2 = bu2f(txo[p2.x * 64 + lane]);
        float g3 = bu2f(txo[p3.x * 64 + lane]);
        float g4 = bu2f(txo[p4.x * 64 + lane]);
        float g5 = bu2f(txo[p5.x * 64 + lane]);
        float g6 = bu2f(txo[p6.x * 64 + lane]);
        float g7 = bu2f(txo[p7.x * 64 + lane]);
        acc += __int_as_float(p0.y) * g0 + __int_as_float(p1.y) * g1 +
               __int_as_float(p2.y) * g2 + __int_as_float(p3.y) * g3;
        acc += __int_as_float(p4.y) * g4 + __int_as_float(p5.y) * g5 +
               __int_as_float(p6.y) * g6 + __int_as_float(p7.y) * g7;
    }
    for (; j < e; ++j) {
        int2 p = pairs[j];
        acc += __int_as_float(p.y) * bu2f(txo[p.x * 64 + lane]);
    }
    txn[wv * 64 + lane] = f2bu(acc);
}

// ---------------- fused polynomial combine + layernorm ----------------

__global__ void k_diffln(float* __restrict__ h, unsigned short* __restrict__ h_bf,
                         const unsigned short* __restrict__ t1, const unsigned short* __restrict__ t2,
                         const unsigned short* __restrict__ t3, const unsigned short* __restrict__ t4,
                         const unsigned short* __restrict__ t5,
                         const float* __restrict__ coeffs,
                         const float* __restrict__ sc, const float* __restrict__ bi,
                         int layer, int last, void* __restrict__ outv,
                         const int* __restrict__ flag) {
    int wv = (blockIdx.x * 256 + threadIdx.x) >> 6;
    int lane = threadIdx.x & 63;
    if (wv >= N_NODES) return;
    int o = wv * 64 + lane;
    float c0 = coeffs[0], c1 = coeffs[1], c2 = coeffs[2],
          c3 = coeffs[3], c4 = coeffs[4], c5 = coeffs[5];
    // LN input = h + (c0*h + sum ck*txk) = (1+c0)*h + sum
    float v = (1.f + c0) * h[o] + c1 * bu2f(t1[o]) + c2 * bu2f(t2[o]) +
              c3 * bu2f(t3[o]) + c4 * bu2f(t4[o]) + c5 * bu2f(t5[o]);
    float m = v;
    for (int off = 1; off < 64; off <<= 1) m += __shfl_xor(m, off, 64);
    m *= (1.f / 64.f);
    float d = v - m;
    float q = d * d;
    for (int off = 1; off < 64; off <<= 1) q += __shfl_xor(q, off, 64);
    float var = q * (1.f / 64.f);
    float y = d / sqrtf(var + 1e-5f) * sc[layer * 64 + lane] + bi[layer * 64 + lane];
    h[o] = y;
    h_bf[o] = f2bu(y);
    if (last) {
        if (*flag) ((float*)outv)[N_EDGES + o] = y;
        else       ((unsigned short*)outv)[N_EDGES + o] = f2bu(y);
    }
}

// ---------------- edge predictor ----------------

__global__ void __launch_bounds__(256) k_uv(const float* __restrict__ h,
                                            const float* __restrict__ W1,
                                            unsigned short* __restrict__ ub,
                                            unsigned short* __restrict__ vb) {
    __shared__ float Wt[128 * 65];
    __shared__ float hs[4 * 64];
    int t = threadIdx.x;
    for (int idx = t; idx < 8192; idx += 256) {
        int f = idx >> 7, j = idx & 127;
        Wt[j * 65 + f] = W1[idx];
    }
    int node0 = blockIdx.x * 4;
    hs[t] = h[node0 * 64 + t];
    __syncthreads();
    int ni = t >> 6, f = t & 63;
    const float* hr = hs + ni * 64;
    float au = 0.f, av = 0.f;
#pragma unroll 8
    for (int j = 0; j < 64; ++j) {
        float xv = hr[j];
        au += Wt[j * 65 + f] * xv;
        av += Wt[(j + 64) * 65 + f] * xv;
    }
    int i = node0 + ni;
    ub[i * 64 + f] = f2bu(au);
    vb[i * 64 + f] = f2bu(av);
}

// MFMA edge predictor: 16 CSR-ordered edges per wave-iteration.
// e1 built directly in A-fragment layout A[m=lane&15][k=(lane>>4)*8+j];
// W2^T preloaded as 4 B-fragments; D layout col=lane&15,row=quad*4+reg.
__global__ void __launch_bounds__(256) k_edgepred(
    const unsigned short* __restrict__ ub, const unsigned short* __restrict__ vb,
    const int4* __restrict__ meta,
    const float* __restrict__ eb1, const float* __restrict__ eW2,
    const float* __restrict__ eb2, const float* __restrict__ eW3,
    const float* __restrict__ eb3,
    void* __restrict__ outv, const int* __restrict__ flag) {
    int t = threadIdx.x;
    int lane = t & 63;
    int m = lane & 15, q = lane >> 4;
    int f32o = *flag;

    // B fragments: B[nt][h][j] = W2[nt*16 + (lane&15)][h*32 + q*8 + j]
    short8 B00, B01, B10, B11;
#pragma unroll
    for (int j = 0; j < 8; ++j) {
        B00[j] = (short)f2bu(eW2[(m) * 64      + q * 8 + j]);
        B01[j] = (short)f2bu(eW2[(m) * 64 + 32 + q * 8 + j]);
        B10[j] = (short)f2bu(eW2[(m + 16) * 64      + q * 8 + j]);
        B11[j] = (short)f2bu(eW2[(m + 16) * 64 + 32 + q * 8 + j]);
    }
    float b1f0[8], b1f1[8];
#pragma unroll
    for (int j = 0; j < 8; ++j) {
        b1f0[j] = eb1[q * 8 + j];
        b1f1[j] = eb1[32 + q * 8 + j];
    }
    float w3a = eW3[m], w3b = eW3[16 + m];
    float b2a = eb2[m], b2b = eb2[16 + m];
    float b3v = eb3[0];

    int gw = blockIdx.x * 4 + (t >> 6);
    const int NW = 1563 * 4;
    for (int tile = gw; tile < N_EDGES / 16; tile += NW) {
        int base = tile << 4;
        int4 md = meta[base + m];  // {col,row,eid,0}
        const unsigned short* up = ub + md.y * 64;
        const unsigned short* vp = vb + md.x * 64;
        uint4 U0 = *(const uint4*)(up + q * 8);
        uint4 U1 = *(const uint4*)(up + 32 + q * 8);
        uint4 V0 = *(const uint4*)(vp + q * 8);
        uint4 V1 = *(const uint4*)(vp + 32 + q * 8);
        short8 A0, A1;
        {
            unsigned uu[4] = {U0.x, U0.y, U0.z, U0.w};
            unsigned vv[4] = {V0.x, V0.y, V0.z, V0.w};
#pragma unroll
            for (int w = 0; w < 4; ++w) {
                float e0 = fmaxf(bu2f(uu[w] & 0xFFFFu) + bu2f(vv[w] & 0xFFFFu) + b1f0[2 * w], 0.f);
                float e1 = fmaxf(bu2f(uu[w] >> 16)     + bu2f(vv[w] >> 16)     + b1f0[2 * w + 1], 0.f);
                A0[2 * w] = (short)f2bu(e0);
                A0[2 * w + 1] = (short)f2bu(e1);
            }
        }
        {
            unsigned uu[4] = {U1.x, U1.y, U1.z, U1.w};
            unsigned vv[4] = {V1.x, V1.y, V1.z, V1.w};
#pragma unroll
            for (int w = 0; w < 4; ++w) {
                float e0 = fmaxf(bu2f(uu[w] & 0xFFFFu) + bu2f(vv[w] & 0xFFFFu) + b1f1[2 * w], 0.f);
                float e1 = fmaxf(bu2f(uu[w] >> 16)     + bu2f(vv[w] >> 16)     + b1f1[2 * w + 1], 0.f);
                A1[2 * w] = (short)f2bu(e0);
                A1[2 * w + 1] = (short)f2bu(e1);
            }
        }
        f32x4 acc0 = {0.f, 0.f, 0.f, 0.f};
        f32x4 acc1 = {0.f, 0.f, 0.f, 0.f};
        acc0 = __builtin_amdgcn_mfma_f32_16x16x32_bf16(A0, B00, acc0, 0, 0, 0);
        acc0 = __builtin_amdgcn_mfma_f32_16x16x32_bf16(A1, B01, acc0, 0, 0, 0);
        acc1 = __builtin_amdgcn_mfma_f32_16x16x32_bf16(A0, B10, acc1, 0, 0, 0);
        acc1 = __builtin_amdgcn_mfma_f32_16x16x32_bf16(A1, B11, acc1, 0, 0, 0);
        float z[4];
#pragma unroll
        for (int rr = 0; rr < 4; ++rr) {
            z[rr] = w3a * fmaxf(acc0[rr] + b2a, 0.f) + w3b * fmaxf(acc1[rr] + b2b, 0.f);
            z[rr] += __shfl_xor(z[rr], 1, 64);
            z[rr] += __shfl_xor(z[rr], 2, 64);
            z[rr] += __shfl_xor(z[rr], 4, 64);
            z[rr] += __shfl_xor(z[rr], 8, 64);
        }
#pragma unroll
        for (int rr = 0; rr < 4; ++rr) {
            int src = (q << 4) + (q << 2) + rr;       // lane holding eid of edge q*4+rr
            int eidr = __shfl(md.z, src, 64);
            if (m == 0) {
                float p = 1.f / (1.f + __expf(-(z[rr] + b3v)));
                if (f32o) ((float*)outv)[eidr] = p;
                else      ((unsigned short*)outv)[eidr] = f2bu(p);
            }
        }
    }
}

// ---------------- launch ----------------

extern "C" void kernel_launch(void* const* d_in, const int* in_sizes, int n_in,
                              void* d_out, int out_size, void* d_ws, size_t ws_size,
                              hipStream_t stream) {
    (void)in_sizes; (void)n_in; (void)out_size; (void)ws_size;
    const void* x_r   = d_in[0];
    const int*  ei    = (const int*)d_in[1];
    const void* ew_r  = d_in[2];

    char* w = (char*)d_ws;
    float* h            = (float*)w;          w += (size_t)NH * 4;   // 12.8 MB
    unsigned short* hbf = (unsigned short*)w; w += (size_t)NH * 2;   // 6.4
    unsigned short* txr = (unsigned short*)w; w += (size_t)NH * 10;  // 32 (5 bufs)
    int2* pairs         = (int2*)w;           w += (size_t)N_EDGES * 8;  // 12.8
    unsigned short* ub  = (unsigned short*)w; w += (size_t)NH * 2;   // 6.4
    unsigned short* vb  = (unsigned short*)w; w += (size_t)NH * 2;   // 6.4
    int* row_ptr        = (int*)w;            w += 200192;
    // converted small weights
    float* cWin = (float*)w; w += 2048;
    float* cbin = (float*)w; w += 256;
    float* ccW1 = (float*)w; w += 26112;
    float* ccb1 = (float*)w; w += 384;
    float* ccW2 = (float*)w; w += 2304;
    float* ccb2 = (float*)w; w += 128;
    float* clns = (float*)w; w += 768;
    float* clnb = (float*)w; w += 768;
    float* ceW1 = (float*)w; w += 32768;
    float* ceb1 = (float*)w; w += 256;
    float* ceW2 = (float*)w; w += 8192;
    float* ceb2 = (float*)w; w += 128;
    float* ceW3 = (float*)w; w += 128;
    float* ceb3 = (float*)w; w += 128;
    char* zero_base = w;
    float* deg   = (float*)w; w += 200192;
    int*   cnt   = (int*)w;   w += 200192;
    int*   fill  = (int*)w;   w += 200192;
    int*   fill2 = (int*)w;   w += 200192;
    float* stats = (float*)w; w += 1024;
    size_t zero_bytes = (size_t)(w - zero_base);
    float* coeffs = (float*)w; w += 128;
    int*   flag   = (int*)w;   w += 128;

    // overlays inside tx region (lifetimes disjoint):
    float* cew = (float*)txr;                 // converts: dead before hop 1
    float* cx  = cew + N_EDGES;
    int4* meta = (int4*)txr;                  // written after last diffln

    unsigned short* tx[5];
    for (int k = 0; k < 5; ++k) tx[k] = txr + (size_t)k * NH;

    hipMemsetAsync(zero_base, 0, zero_bytes, stream);

    k_detect<<<1, 64, 0, stream>>>(ew_r, flag);
    k_conv_big<<<7813, 256, 0, stream>>>(x_r, ew_r, cx, cew, flag);

    ConvArgs ca;
    const void* srcs[14] = {d_in[3], d_in[4], d_in[5], d_in[6], d_in[7], d_in[8], d_in[9],
                            d_in[10], d_in[11], d_in[12], d_in[13], d_in[14], d_in[15], d_in[16]};
    float* dsts[14] = {cWin, cbin, ccW1, ccb1, ccW2, ccb2, clns,
                       clnb, ceW1, ceb1, ceW2, ceb2, ceW3, ceb3};
    int sizes[14] = {512, 64, 6528, 96, 576, 18, 192, 192, 8192, 64, 2048, 32, 32, 1};
    int c = 0;
    for (int i = 0; i < 14; ++i) { ca.src[i] = srcs[i]; ca.dst[i] = dsts[i]; ca.cum[i] = c; c += sizes[i]; }
    ca.cum[14] = c;
    k_conv_small<<<(c + 255) / 256, 256, 0, stream>>>(ca, flag);

    k_setup<<<6250, 256, 0, stream>>>(ei, cew, deg, cnt);
    k_dis<<<196, 256, 0, stream>>>(deg);
    k_scan<<<1, 1024, 0, stream>>>(cnt, row_ptr);
    k_fill<<<6250, 256, 0, stream>>>(ei, cew, deg, row_ptr, fill, pairs);
    k_inproj<<<12500, 256, 0, stream>>>(cx, cWin, cbin, h, hbf);

    for (int l = 0; l < NLAYERS; ++l) {
        k_stats<<<400, 256, 0, stream>>>(h, stats + l * 80);
        k_coeffs<<<1, 64, 0, stream>>>(stats + l * 80, ccW1, ccb1, ccW2, ccb2, l,
                                       coeffs + l * 8);
        const unsigned short* src = hbf;
        for (int k = 0; k < 5; ++k) {
            k_spmm<<<12500, 256, 0, stream>>>(src, tx[k], row_ptr, pairs);
            src = tx[k];
        }
        k_diffln<<<12500, 256, 0, stream>>>(h, hbf, tx[0], tx[1], tx[2], tx[3], tx[4],
                                            coeffs + l * 8, clns, clnb, l,
                                            (l == NLAYERS - 1) ? 1 : 0, d_out, flag);
    }

    k_uv<<<12500, 256, 0, stream>>>(h, ceW1, ub, vb);
    k_fill2<<<6250, 256, 0, stream>>>(ei, row_ptr, fill2, meta);
    k_edgepred<<<1563, 256, 0, stream>>>(ub, vb, meta, ceb1, ceW2, ceb2, ceW3, ceb3,
                                         d_out, flag);
}

// Round 4
// 1219.837 us; speedup vs baseline: 1.5813x; 1.2526x over previous
//
#include <hip/hip_runtime.h>
#include <hip/hip_bf16.h>

typedef __hip_bfloat16 bf16;
typedef __attribute__((ext_vector_type(8))) short short8;
typedef __attribute__((ext_vector_type(4))) float f32x4;

#define N_NODES 50000
#define N_EDGES 1600000
#define FIN 8
#define HD 64
#define NH (N_NODES * HD)
#define NLAYERS 3

__device__ __forceinline__ float b2f(bf16 v) { return __bfloat162float(v); }
__device__ __forceinline__ float bu2f(unsigned int u) { return __uint_as_float(u << 16); }
__device__ __forceinline__ unsigned short f2bu(float f) {
    unsigned int x = __float_as_uint(f);
    unsigned int r = x + 0x7FFFu + ((x >> 16) & 1u);
    return (unsigned short)(r >> 16);
}

// ---------------- dtype detection ----------------
__global__ void k_detect(const void* __restrict__ ew, int* __restrict__ flag) {
    int ok = 1;
    for (int i = threadIdx.x; i < 512; i += 64) {
        float v = b2f(((const bf16*)ew)[i]);
        if (!(v >= 0.f && v <= 1.f)) ok = 0;
    }
    unsigned long long m = __ballot(ok);
    if (threadIdx.x == 0) *flag = (m == 0xFFFFFFFFFFFFFFFFull) ? 0 : 1;
}

struct ConvArgs {
    const void* src[14];
    float* dst[14];
    int cum[15];
};

// one conversion kernel: x (400000), ew (1600000), then 14 small weight arrays
__global__ void k_conv(const void* __restrict__ xs, const void* __restrict__ es,
                       float* __restrict__ cx, float* __restrict__ cew,
                       ConvArgs a, const int* __restrict__ flag) {
    int idx = blockIdx.x * 256 + threadIdx.x;
    int f32 = *flag;
    if (idx < 400000) {
        cx[idx] = f32 ? ((const float*)xs)[idx] : bu2f(((const unsigned short*)xs)[idx]);
    } else if (idx < 2000000) {
        int o = idx - 400000;
        cew[o] = f32 ? ((const float*)es)[o] : bu2f(((const unsigned short*)es)[o]);
    } else {
        int q = idx - 2000000;
        if (q >= a.cum[14]) return;
        int s = 0;
        while (q >= a.cum[s + 1]) ++s;
        int off = q - a.cum[s];
        if (f32) a.dst[s][off] = ((const float*)a.src[s])[off];
        else     a.dst[s][off] = bu2f(((const unsigned short*)a.src[s])[off]);
    }
}

// ---------------- setup: degree + count histograms ----------------

__global__ void k_setup(const int* __restrict__ ei, const float* __restrict__ w,
                        float* __restrict__ deg, int* __restrict__ cnt) {
    int e = blockIdx.x * 256 + threadIdx.x;
    if (e < N_EDGES) {
        atomicAdd(&deg[ei[N_EDGES + e]], w[e]);
        atomicAdd(&cnt[ei[e]], 1);
    }
}

// 2-pass scan: per-thread chunk of 49, one 1024-wide Hillis-Steele
__global__ void k_scan(const int* __restrict__ cnt, int* __restrict__ row_ptr) {
    __shared__ int part[1024];
    int t = threadIdx.x;
    const int CH = 49;
    int base = t * CH;
    int s = 0;
    for (int i = 0; i < CH; ++i) {
        int idx = base + i;
        if (idx < N_NODES) s += cnt[idx];
    }
    part[t] = s;
    __syncthreads();
    int val = s;
    for (int off = 1; off < 1024; off <<= 1) {
        int other = (t >= off) ? part[t - off] : 0;
        __syncthreads();
        val += other;
        part[t] = val;
        __syncthreads();
    }
    int run = val - s;
    for (int i = 0; i < CH; ++i) {
        int idx = base + i;
        if (idx <= N_NODES) row_ptr[idx] = run;
        if (idx < N_NODES) run += cnt[idx];
    }
}

// fused CSR fill: pairs[pos] = {col | row<<16, bits(norm)}, eid[pos] = e
__global__ void k_fill(const int* __restrict__ ei, const float* __restrict__ w,
                       const float* __restrict__ deg,
                       const int* __restrict__ row_ptr, int* __restrict__ fill,
                       int2* __restrict__ pairs, int* __restrict__ eid) {
    int e = blockIdx.x * 256 + threadIdx.x;
    if (e < N_EDGES) {
        int r = ei[e], c = ei[N_EDGES + e];
        float dr = fminf(rsqrtf(deg[r]), 1e6f);   // rsqrt(0)=inf -> min -> 1e6
        float dc = fminf(rsqrtf(deg[c]), 1e6f);
        int pos = row_ptr[r] + atomicAdd(&fill[r], 1);
        int2 p;
        p.x = c | (r << 16);
        p.y = __float_as_int(dr * w[e] * dc);
        pairs[pos] = p;
        eid[pos] = e;
    }
}

// ---------------- input projection ----------------

__global__ void k_inproj(const float* __restrict__ x, const float* __restrict__ W,
                         const float* __restrict__ b, float* __restrict__ h,
                         unsigned short* __restrict__ h_bf) {
    __shared__ float Wt[FIN * HD];
    __shared__ float bs[HD];
    int t = threadIdx.x;
    for (int idx = t; idx < FIN * HD; idx += 256) {
        int f = idx >> 3, j = idx & 7;
        Wt[j * 64 + f] = W[idx];
    }
    if (t < 64) bs[t] = b[t];
    __syncthreads();
    int gid = blockIdx.x * 256 + t;
    if (gid < NH) {
        int i = gid >> 6, f = gid & 63;
        const float* xr = x + i * FIN;
        float acc = bs[f];
#pragma unroll
        for (int j = 0; j < FIN; ++j) acc += xr[j] * Wt[j * 64 + f];
        h[gid] = acc;
        h_bf[gid] = f2bu(acc);
    }
}

// ---------------- stats + coefficient MLP ----------------

__global__ void k_stats(const float* __restrict__ h, float* __restrict__ stats) {
    __shared__ float ssum[256], ssq[256];
    int t = threadIdx.x;
    float ls = 0.f, lq = 0.f;
    for (int idx = blockIdx.x * 256 + t; idx < NH; idx += 102400) {
        float v = h[idx];
        ls += v; lq += v * v;
    }
    ssum[t] = ls; ssq[t] = lq;
    __syncthreads();
    if (t < 64) {
        float a = ssum[t] + ssum[t + 64] + ssum[t + 128] + ssum[t + 192];
        atomicAdd(&stats[t], a);
        float q = ssq[t] + ssq[t + 64] + ssq[t + 128] + ssq[t + 192];
        for (int off = 32; off; off >>= 1) q += __shfl_down(q, off, 64);
        if (t == 0) atomicAdd(&stats[64], q);
    }
}

__global__ void k_coeffs(const float* __restrict__ stats,
                         const float* __restrict__ W1, const float* __restrict__ b1,
                         const float* __restrict__ W2, const float* __restrict__ b2,
                         int layer, float* __restrict__ coeffs) {
    __shared__ float ci[68];
    __shared__ float hid[32];
    __shared__ float lg[6];
    int t = threadIdx.x;
    float sf = stats[t];
    float tot = sf;
    for (int off = 1; off < 64; off <<= 1) tot += __shfl_xor(tot, off, 64);
    ci[t] = sf / (float)N_NODES;
    if (t == 0) {
        float sumsq = stats[64];
        float mean = tot / (float)NH;
        float var = (sumsq - (float)NH * mean * mean) / (float)(NH - 1);
        ci[64] = mean;
        ci[65] = sqrtf(fmaxf(var, 0.f));
        ci[66] = (float)N_NODES;
        ci[67] = (float)N_EDGES;
    }
    __syncthreads();
    if (t < 32) {
        float a = b1[layer * 32 + t];
        const float* wr = W1 + (layer * 32 + t) * 68;
        for (int j = 0; j < 68; ++j) a += ci[j] * wr[j];
        hid[t] = fmaxf(a, 0.f);
    }
    __syncthreads();
    if (t < 6) {
        float a = b2[layer * 6 + t];
        const float* wr = W2 + (layer * 6 + t) * 32;
        for (int g = 0; g < 32; ++g) a += hid[g] * wr[g];
        lg[t] = a;
    }
    __syncthreads();
    if (t == 0) {
        float mx = lg[0];
        for (int p = 1; p < 6; ++p) mx = fmaxf(mx, lg[p]);
        float s = 0.f, e[6];
        for (int p = 0; p < 6; ++p) { e[p] = expf(lg[p] - mx); s += e[p]; }
        for (int p = 0; p < 6; ++p) coeffs[p] = e[p] / s;
    }
}

// ---------------- SpMM hop: wave per node, lane = feature ----------------
// Row extents and pairs stream are wave-uniform -> force scalar (SMEM) path.

__global__ void __launch_bounds__(256) k_spmm(
    const unsigned short* __restrict__ txo, unsigned short* __restrict__ txn,
    const int* __restrict__ row_ptr, const int2* __restrict__ pairs) {
    int lane = threadIdx.x & 63;
    int wv = __builtin_amdgcn_readfirstlane((int)(blockIdx.x * 4 + (threadIdx.x >> 6)));
    int s = __builtin_amdgcn_readfirstlane(row_ptr[wv]);
    int e = __builtin_amdgcn_readfirstlane(row_ptr[wv + 1]);
    float acc = 0.f;
    int j = s;
    for (; j + 7 < e; j += 8) {
        int2 p0 = pairs[j],     p1 = pairs[j + 1], p2 = pairs[j + 2], p3 = pairs[j + 3];
        int2 p4 = pairs[j + 4], p5 = pairs[j + 5], p6 = pairs[j + 6], p7 = pairs[j + 7];
        int c0 = p0.x & 0xFFFF, c1 = p1.x & 0xFFFF, c2 = p2.x & 0xFFFF, c3 = p3.x & 0xFFFF;
        int c4 = p4.x & 0xFFFF, c5 = p5.x & 0xFFFF, c6 = p6.x & 0xFFFF, c7 = p7.x & 0xFFFF;
        float g0 = bu2f(txo[c0 * 64 + lane]);
        float g1 = bu2f(txo[c1 * 64 + lane]);
        float g2 = bu2f(txo[c2 * 64 + lane]);
        float g3 = bu2f(txo[c3 * 64 + lane]);
        float g4 = bu2f(txo[c4 * 64 + lane]);
        float g5 = bu2f(txo[c5 * 64 + lane]);
        float g6 = bu2f(txo[c6 * 64 + lane]);
        float g7 = bu2f(txo[c7 * 64 + lane]);
        acc += __int_as_float(p0.y) * g0 + __int_as_float(p1.y) * g1 +
               __int_as_float(p2.y) * g2 + __int_as_float(p3.y) * g3;
        acc += __int_as_float(p4.y) * g4 + __int_as_float(p5.y) * g5 +
               __int_as_float(p6.y) * g6 + __int_as_float(p7.y) * g7;
    }
    for (; j < e; ++j) {
        int2 p = pairs[j];
        acc += __int_as_float(p.y) * bu2f(txo[(p.x & 0xFFFF) * 64 + lane]);
    }
    txn[wv * 64 + lane] = f2bu(acc);
}

// ---------------- fused polynomial combine + layernorm ----------------

__global__ void k_diffln(float* __restrict__ h, unsigned short* __restrict__ h_bf,
                         const unsigned short* __restrict__ t1, const unsigned short* __restrict__ t2,
                         const unsigned short* __restrict__ t3, const unsigned short* __restrict__ t4,
                         const unsigned short* __restrict__ t5,
                         const float* __restrict__ coeffs,
                         const float* __restrict__ sc, const float* __restrict__ bi,
                         int layer, int last, void* __restrict__ outv,
                         const int* __restrict__ flag) {
    int wv = (blockIdx.x * 256 + threadIdx.x) >> 6;
    int lane = threadIdx.x & 63;
    if (wv >= N_NODES) return;
    int o = wv * 64 + lane;
    float c0 = coeffs[0], c1 = coeffs[1], c2 = coeffs[2],
          c3 = coeffs[3], c4 = coeffs[4], c5 = coeffs[5];
    float v = (1.f + c0) * h[o] + c1 * bu2f(t1[o]) + c2 * bu2f(t2[o]) +
              c3 * bu2f(t3[o]) + c4 * bu2f(t4[o]) + c5 * bu2f(t5[o]);
    float m = v;
    for (int off = 1; off < 64; off <<= 1) m += __shfl_xor(m, off, 64);
    m *= (1.f / 64.f);
    float d = v - m;
    float q = d * d;
    for (int off = 1; off < 64; off <<= 1) q += __shfl_xor(q, off, 64);
    float var = q * (1.f / 64.f);
    float y = d / sqrtf(var + 1e-5f) * sc[layer * 64 + lane] + bi[layer * 64 + lane];
    h[o] = y;
    h_bf[o] = f2bu(y);
    if (last) {
        if (*flag) ((float*)outv)[N_EDGES + o] = y;
        else       ((unsigned short*)outv)[N_EDGES + o] = f2bu(y);
    }
}

// ---------------- edge predictor ----------------

__global__ void __launch_bounds__(256) k_uv(const float* __restrict__ h,
                                            const float* __restrict__ W1,
                                            unsigned short* __restrict__ ub,
                                            unsigned short* __restrict__ vb) {
    __shared__ float Wt[128 * 65];
    __shared__ float hs[4 * 64];
    int t = threadIdx.x;
    for (int idx = t; idx < 8192; idx += 256) {
        int f = idx >> 7, j = idx & 127;
        Wt[j * 65 + f] = W1[idx];
    }
    int node0 = blockIdx.x * 4;
    hs[t] = h[node0 * 64 + t];
    __syncthreads();
    int ni = t >> 6, f = t & 63;
    const float* hr = hs + ni * 64;
    float au = 0.f, av = 0.f;
#pragma unroll 8
    for (int j = 0; j < 64; ++j) {
        float xv = hr[j];
        au += Wt[j * 65 + f] * xv;
        av += Wt[(j + 64) * 65 + f] * xv;
    }
    int i = node0 + ni;
    ub[i * 64 + f] = f2bu(au);
    vb[i * 64 + f] = f2bu(av);
}

// MFMA edge predictor: 16 CSR-ordered edges per wave-iteration.
__global__ void __launch_bounds__(256) k_edgepred(
    const unsigned short* __restrict__ ub, const unsigned short* __restrict__ vb,
    const int2* __restrict__ pairs, const int* __restrict__ eid,
    const float* __restrict__ eb1, const float* __restrict__ eW2,
    const float* __restrict__ eb2, const float* __restrict__ eW3,
    const float* __restrict__ eb3,
    void* __restrict__ outv, const int* __restrict__ flag) {
    int t = threadIdx.x;
    int lane = t & 63;
    int m = lane & 15, q = lane >> 4;
    int f32o = *flag;

    short8 B00, B01, B10, B11;
#pragma unroll
    for (int j = 0; j < 8; ++j) {
        B00[j] = (short)f2bu(eW2[(m) * 64      + q * 8 + j]);
        B01[j] = (short)f2bu(eW2[(m) * 64 + 32 + q * 8 + j]);
        B10[j] = (short)f2bu(eW2[(m + 16) * 64      + q * 8 + j]);
        B11[j] = (short)f2bu(eW2[(m + 16) * 64 + 32 + q * 8 + j]);
    }
    float b1f0[8], b1f1[8];
#pragma unroll
    for (int j = 0; j < 8; ++j) {
        b1f0[j] = eb1[q * 8 + j];
        b1f1[j] = eb1[32 + q * 8 + j];
    }
    float w3a = eW3[m], w3b = eW3[16 + m];
    float b2a = eb2[m], b2b = eb2[16 + m];
    float b3v = eb3[0];

    int gw = blockIdx.x * 4 + (t >> 6);
    const int NW = 1563 * 4;
    for (int tile = gw; tile < N_EDGES / 16; tile += NW) {
        int base = tile << 4;
        int2 pm = pairs[base + m];
        int col = pm.x & 0xFFFF;
        int row = ((unsigned)pm.x) >> 16;
        int eidv = eid[base + m];
        const unsigned short* up = ub + row * 64;
        const unsigned short* vp = vb + col * 64;
        uint4 U0 = *(const uint4*)(up + q * 8);
        uint4 U1 = *(const uint4*)(up + 32 + q * 8);
        uint4 V0 = *(const uint4*)(vp + q * 8);
        uint4 V1 = *(const uint4*)(vp + 32 + q * 8);
        short8 A0, A1;
        {
            unsigned uu[4] = {U0.x, U0.y, U0.z, U0.w};
            unsigned vv[4] = {V0.x, V0.y, V0.z, V0.w};
#pragma unroll
            for (int w = 0; w < 4; ++w) {
                float e0 = fmaxf(bu2f(uu[w] & 0xFFFFu) + bu2f(vv[w] & 0xFFFFu) + b1f0[2 * w], 0.f);
                float e1 = fmaxf(bu2f(uu[w] >> 16)     + bu2f(vv[w] >> 16)     + b1f0[2 * w + 1], 0.f);
                A0[2 * w] = (short)f2bu(e0);
                A0[2 * w + 1] = (short)f2bu(e1);
            }
        }
        {
            unsigned uu[4] = {U1.x, U1.y, U1.z, U1.w};
            unsigned vv[4] = {V1.x, V1.y, V1.z, V1.w};
#pragma unroll
            for (int w = 0; w < 4; ++w) {
                float e0 = fmaxf(bu2f(uu[w] & 0xFFFFu) + bu2f(vv[w] & 0xFFFFu) + b1f1[2 * w], 0.f);
                float e1 = fmaxf(bu2f(uu[w] >> 16)     + bu2f(vv[w] >> 16)     + b1f1[2 * w + 1], 0.f);
                A1[2 * w] = (short)f2bu(e0);
                A1[2 * w + 1] = (short)f2bu(e1);
            }
        }
        f32x4 acc0 = {0.f, 0.f, 0.f, 0.f};
        f32x4 acc1 = {0.f, 0.f, 0.f, 0.f};
        acc0 = __builtin_amdgcn_mfma_f32_16x16x32_bf16(A0, B00, acc0, 0, 0, 0);
        acc0 = __builtin_amdgcn_mfma_f32_16x16x32_bf16(A1, B01, acc0, 0, 0, 0);
        acc1 = __builtin_amdgcn_mfma_f32_16x16x32_bf16(A0, B10, acc1, 0, 0, 0);
        acc1 = __builtin_amdgcn_mfma_f32_16x16x32_bf16(A1, B11, acc1, 0, 0, 0);
        float z[4];
#pragma unroll
        for (int rr = 0; rr < 4; ++rr) {
            z[rr] = w3a * fmaxf(acc0[rr] + b2a, 0.f) + w3b * fmaxf(acc1[rr] + b2b, 0.f);
            z[rr] += __shfl_xor(z[rr], 1, 64);
            z[rr] += __shfl_xor(z[rr], 2, 64);
            z[rr] += __shfl_xor(z[rr], 4, 64);
            z[rr] += __shfl_xor(z[rr], 8, 64);
        }
#pragma unroll
        for (int rr = 0; rr < 4; ++rr) {
            int src = (q << 4) + (q << 2) + rr;
            int eidr = __shfl(eidv, src, 64);
            if (m == 0) {
                float p = 1.f / (1.f + __expf(-(z[rr] + b3v)));
                if (f32o) ((float*)outv)[eidr] = p;
                else      ((unsigned short*)outv)[eidr] = f2bu(p);
            }
        }
    }
}

// ---------------- launch ----------------

extern "C" void kernel_launch(void* const* d_in, const int* in_sizes, int n_in,
                              void* d_out, int out_size, void* d_ws, size_t ws_size,
                              hipStream_t stream) {
    (void)in_sizes; (void)n_in; (void)out_size; (void)ws_size;
    const void* x_r   = d_in[0];
    const int*  ei    = (const int*)d_in[1];
    const void* ew_r  = d_in[2];

    char* w = (char*)d_ws;
    float* h            = (float*)w;          w += (size_t)NH * 4;   // 12.8 MB
    unsigned short* hbf = (unsigned short*)w; w += (size_t)NH * 2;   // 6.4
    unsigned short* txr = (unsigned short*)w; w += (size_t)NH * 10;  // 32 (5 bufs)
    int2* pairs         = (int2*)w;           w += (size_t)N_EDGES * 8;  // 12.8
    int*  eidA          = (int*)w;            w += (size_t)N_EDGES * 4;  // 6.4
    int* row_ptr        = (int*)w;            w += 200192;
    float* cWin = (float*)w; w += 2048;
    float* cbin = (float*)w; w += 256;
    float* ccW1 = (float*)w; w += 26112;
    float* ccb1 = (float*)w; w += 384;
    float* ccW2 = (float*)w; w += 2304;
    float* ccb2 = (float*)w; w += 128;
    float* clns = (float*)w; w += 768;
    float* clnb = (float*)w; w += 768;
    float* ceW1 = (float*)w; w += 32768;
    float* ceb1 = (float*)w; w += 256;
    float* ceW2 = (float*)w; w += 8192;
    float* ceb2 = (float*)w; w += 128;
    float* ceW3 = (float*)w; w += 128;
    float* ceb3 = (float*)w; w += 128;
    char* zero_base = w;
    float* deg   = (float*)w; w += 200192;
    int*   cnt   = (int*)w;   w += 200192;
    int*   fill  = (int*)w;   w += 200192;
    float* stats = (float*)w; w += 1024;
    size_t zero_bytes = (size_t)(w - zero_base);
    float* coeffs = (float*)w; w += 128;
    int*   flag   = (int*)w;   w += 128;

    // overlays inside tx region (lifetimes disjoint):
    float* cew = (float*)txr;                 // converts: dead before hop 1
    float* cx  = cew + N_EDGES;
    unsigned short* tx[5];
    for (int k = 0; k < 5; ++k) tx[k] = txr + (size_t)k * NH;
    unsigned short* ub = tx[0];               // k_uv runs after last diffln: tx dead
    unsigned short* vb = tx[1];

    hipMemsetAsync(zero_base, 0, zero_bytes, stream);

    k_detect<<<1, 64, 0, stream>>>(ew_r, flag);

    ConvArgs ca;
    const void* srcs[14] = {d_in[3], d_in[4], d_in[5], d_in[6], d_in[7], d_in[8], d_in[9],
                            d_in[10], d_in[11], d_in[12], d_in[13], d_in[14], d_in[15], d_in[16]};
    float* dsts[14] = {cWin, cbin, ccW1, ccb1, ccW2, ccb2, clns,
                       clnb, ceW1, ceb1, ceW2, ceb2, ceW3, ceb3};
    int sizes[14] = {512, 64, 6528, 96, 576, 18, 192, 192, 8192, 64, 2048, 32, 32, 1};
    int c = 0;
    for (int i = 0; i < 14; ++i) { ca.src[i] = srcs[i]; ca.dst[i] = dsts[i]; ca.cum[i] = c; c += sizes[i]; }
    ca.cum[14] = c;
    k_conv<<<(2000000 + c + 255) / 256, 256, 0, stream>>>(x_r, ew_r, cx, cew, ca, flag);

    k_setup<<<6250, 256, 0, stream>>>(ei, cew, deg, cnt);
    k_scan<<<1, 1024, 0, stream>>>(cnt, row_ptr);
    k_fill<<<6250, 256, 0, stream>>>(ei, cew, deg, row_ptr, fill, pairs, eidA);
    k_inproj<<<12500, 256, 0, stream>>>(cx, cWin, cbin, h, hbf);

    for (int l = 0; l < NLAYERS; ++l) {
        k_stats<<<400, 256, 0, stream>>>(h, stats + l * 80);
        k_coeffs<<<1, 64, 0, stream>>>(stats + l * 80, ccW1, ccb1, ccW2, ccb2, l,
                                       coeffs + l * 8);
        const unsigned short* src = hbf;
        for (int k = 0; k < 5; ++k) {
            k_spmm<<<12500, 256, 0, stream>>>(src, tx[k], row_ptr, pairs);
            src = tx[k];
        }
        k_diffln<<<12500, 256, 0, stream>>>(h, hbf, tx[0], tx[1], tx[2], tx[3], tx[4],
                                            coeffs + l * 8, clns, clnb, l,
                                            (l == NLAYERS - 1) ? 1 : 0, d_out, flag);
    }

    k_uv<<<12500, 256, 0, stream>>>(h, ceW1, ub, vb);
    k_edgepred<<<1563, 256, 0, stream>>>(ub, vb, pairs, eidA, ceb1, ceW2, ceb2, ceW3, ceb3,
                                         d_out, flag);
}

// Round 5
// 1213.621 us; speedup vs baseline: 1.5894x; 1.0051x over previous
//
#include <hip/hip_runtime.h>
#include <hip/hip_bf16.h>

typedef __hip_bfloat16 bf16;
typedef __attribute__((ext_vector_type(8))) short short8;
typedef __attribute__((ext_vector_type(4))) float f32x4;

#define N_NODES 50000
#define N_EDGES 1600000
#define FIN 8
#define HD 64
#define NH (N_NODES * HD)
#define NLAYERS 3

#define NSLICE 32            // edge slices (E/NSLICE = 50000 exactly)
#define ESLICE (N_EDGES / NSLICE)
#define SUBSZ 8192           // nodes per subrange
#define NSUB 7               // ceil(50000/8192)
#define PADN (NSUB * SUBSZ)  // 57344 padded per-slice histogram stride

__device__ __forceinline__ float b2f(bf16 v) { return __bfloat162float(v); }
__device__ __forceinline__ float bu2f(unsigned int u) { return __uint_as_float(u << 16); }
__device__ __forceinline__ unsigned short f2bu(float f) {
    unsigned int x = __float_as_uint(f);
    unsigned int r = x + 0x7FFFu + ((x >> 16) & 1u);
    return (unsigned short)(r >> 16);
}

// ---------------- dtype detection ----------------
__global__ void k_detect(const void* __restrict__ ew, int* __restrict__ flag) {
    int ok = 1;
    for (int i = threadIdx.x; i < 512; i += 64) {
        float v = b2f(((const bf16*)ew)[i]);
        if (!(v >= 0.f && v <= 1.f)) ok = 0;
    }
    unsigned long long m = __ballot(ok);
    if (threadIdx.x == 0) *flag = (m == 0xFFFFFFFFFFFFFFFFull) ? 0 : 1;
}

struct ConvArgs {
    const void* src[14];
    float* dst[14];
    int cum[15];
};

__global__ void k_conv(const void* __restrict__ xs, const void* __restrict__ es,
                       float* __restrict__ cx, float* __restrict__ cew,
                       ConvArgs a, const int* __restrict__ flag) {
    int idx = blockIdx.x * 256 + threadIdx.x;
    int f32 = *flag;
    if (idx < 400000) {
        cx[idx] = f32 ? ((const float*)xs)[idx] : bu2f(((const unsigned short*)xs)[idx]);
    } else if (idx < 2000000) {
        int o = idx - 400000;
        cew[o] = f32 ? ((const float*)es)[o] : bu2f(((const unsigned short*)es)[o]);
    } else {
        int q = idx - 2000000;
        if (q >= a.cum[14]) return;
        int s = 0;
        while (q >= a.cum[s + 1]) ++s;
        int off = q - a.cum[s];
        if (f32) a.dst[s][off] = ((const float*)a.src[s])[off];
        else     a.dst[s][off] = bu2f(((const unsigned short*)a.src[s])[off]);
    }
}

// ---------------- atomic-free histograms: LDS privatized by (slice, subrange) ----------------
// pcnt[slice*PADN + n] = #edges with row n in slice; pdeg likewise (weighted, col)
__global__ void __launch_bounds__(256) k_hist(const int* __restrict__ ei,
                                              const float* __restrict__ cew,
                                              int* __restrict__ pcnt,
                                              float* __restrict__ pdeg) {
    __shared__ int cntl[SUBSZ];
    __shared__ float degl[SUBSZ];
    int slice = blockIdx.x & 31;
    int sub = blockIdx.x >> 5;
    int t = threadIdx.x;
    for (int i = t; i < SUBSZ; i += 256) { cntl[i] = 0; degl[i] = 0.f; }
    __syncthreads();
    int ebase = slice * ESLICE;
    for (int el = t; el < ESLICE; el += 256) {
        int e = ebase + el;
        int r = ei[e];
        int c = ei[N_EDGES + e];
        if ((r >> 13) == sub) atomicAdd(&cntl[r & (SUBSZ - 1)], 1);
        if ((c >> 13) == sub) atomicAdd(&degl[c & (SUBSZ - 1)], cew[e]);
    }
    __syncthreads();
    int obase = slice * PADN + sub * SUBSZ;
    for (int i = t; i < SUBSZ; i += 256) {
        pcnt[obase + i] = cntl[i];
        pdeg[obase + i] = degl[i];
    }
}

// merge partials: cnt[n], deg[n], and per-slice exclusive prefix pcnt_pref[s*N_NODES+n]
__global__ void k_merge(const int* __restrict__ pcnt, const float* __restrict__ pdeg,
                        int* __restrict__ cnt, float* __restrict__ deg,
                        int* __restrict__ pref) {
    int n = blockIdx.x * 256 + threadIdx.x;
    if (n >= N_NODES) return;
    int run = 0;
    float d = 0.f;
#pragma unroll 8
    for (int s = 0; s < NSLICE; ++s) {
        pref[s * N_NODES + n] = run;
        run += pcnt[s * PADN + n];
        d += pdeg[s * PADN + n];
    }
    cnt[n] = run;
    deg[n] = d;
}

// 2-pass scan: per-thread chunk of 49, one 1024-wide Hillis-Steele
__global__ void k_scan(const int* __restrict__ cnt, int* __restrict__ row_ptr) {
    __shared__ int part[1024];
    int t = threadIdx.x;
    const int CH = 49;
    int base = t * CH;
    int s = 0;
    for (int i = 0; i < CH; ++i) {
        int idx = base + i;
        if (idx < N_NODES) s += cnt[idx];
    }
    part[t] = s;
    __syncthreads();
    int val = s;
    for (int off = 1; off < 1024; off <<= 1) {
        int other = (t >= off) ? part[t - off] : 0;
        __syncthreads();
        val += other;
        part[t] = val;
        __syncthreads();
    }
    int run = val - s;
    for (int i = 0; i < CH; ++i) {
        int idx = base + i;
        if (idx <= N_NODES) row_ptr[idx] = run;
        if (idx < N_NODES) run += cnt[idx];
    }
}

// atomic-free CSR placement: LDS running offsets seeded from row_ptr + pref
// pairs4[pos] = (col<<16) | bf16bits(norm);  pairs8[pos] = {col | row<<16, eid}
__global__ void __launch_bounds__(256) k_place(const int* __restrict__ ei,
                                               const float* __restrict__ cew,
                                               const float* __restrict__ deg,
                                               const int* __restrict__ row_ptr,
                                               const int* __restrict__ pref,
                                               unsigned int* __restrict__ pairs4,
                                               int2* __restrict__ pairs8) {
    __shared__ int off[SUBSZ];
    int slice = blockIdx.x & 31;
    int sub = blockIdx.x >> 5;
    int t = threadIdx.x;
    int nbase = sub * SUBSZ;
    for (int i = t; i < SUBSZ; i += 256) {
        int n = nbase + i;
        off[i] = (n < N_NODES) ? row_ptr[n] + pref[slice * N_NODES + n] : 0;
    }
    __syncthreads();
    int ebase = slice * ESLICE;
    for (int el = t; el < ESLICE; el += 256) {
        int e = ebase + el;
        int r = ei[e];
        if ((r >> 13) == sub) {
            int c = ei[N_EDGES + e];
            float w = cew[e];
            float dr = fminf(rsqrtf(deg[r]), 1e6f);
            float dc = fminf(rsqrtf(deg[c]), 1e6f);
            int pos = atomicAdd(&off[r & (SUBSZ - 1)], 1);
            pairs4[pos] = ((unsigned)c << 16) | (unsigned)f2bu(dr * w * dc);
            int2 p8;
            p8.x = c | (r << 16);
            p8.y = e;
            pairs8[pos] = p8;
        }
    }
}

// wave-per-row bitonic sort of pairs4 by col (high 16 bits); rows >128 left unsorted (rare, still correct)
__global__ void __launch_bounds__(256) k_sort(const int* __restrict__ row_ptr,
                                              unsigned int* __restrict__ pairs4) {
    int wv = (blockIdx.x * 256 + threadIdx.x) >> 6;
    int lane = threadIdx.x & 63;
    if (wv >= N_NODES) return;
    int s = row_ptr[wv], e = row_ptr[wv + 1];
    int len = e - s;
    if (len <= 1 || len > 128) return;
    unsigned v0 = (s + lane < e) ? pairs4[s + lane] : 0xFFFFFFFFu;
    unsigned v1 = (s + 64 + lane < e) ? pairs4[s + 64 + lane] : 0xFFFFFFFFu;
#pragma unroll
    for (int k = 2; k <= 128; k <<= 1) {
#pragma unroll
        for (int j = k >> 1; j >= 1; j >>= 1) {
            if (j == 64) {
                unsigned lo = min(v0, v1), hi = max(v0, v1);
                v0 = lo; v1 = hi;
            } else {
                unsigned o0 = (unsigned)__shfl_xor((int)v0, j, 64);
                unsigned o1 = (unsigned)__shfl_xor((int)v1, j, 64);
                bool lower = ((lane & j) == 0);
                bool up0 = ((lane & k) == 0) || (k == 128);
                bool up1 = (((lane | 64) & k) == 0) || (k == 128);
                v0 = (lower == up0) ? min(v0, o0) : max(v0, o0);
                v1 = (lower == up1) ? min(v1, o1) : max(v1, o1);
            }
        }
    }
    if (s + lane < e) pairs4[s + lane] = v0;
    if (s + 64 + lane < e) pairs4[s + 64 + lane] = v1;
}

// ---------------- input projection ----------------

__global__ void k_inproj(const float* __restrict__ x, const float* __restrict__ W,
                         const float* __restrict__ b, float* __restrict__ h,
                         unsigned short* __restrict__ h_bf) {
    __shared__ float Wt[FIN * HD];
    __shared__ float bs[HD];
    int t = threadIdx.x;
    for (int idx = t; idx < FIN * HD; idx += 256) {
        int f = idx >> 3, j = idx & 7;
        Wt[j * 64 + f] = W[idx];
    }
    if (t < 64) bs[t] = b[t];
    __syncthreads();
    int gid = blockIdx.x * 256 + t;
    if (gid < NH) {
        int i = gid >> 6, f = gid & 63;
        const float* xr = x + i * FIN;
        float acc = bs[f];
#pragma unroll
        for (int j = 0; j < FIN; ++j) acc += xr[j] * Wt[j * 64 + f];
        h[gid] = acc;
        h_bf[gid] = f2bu(acc);
    }
}

// ---------------- stats + coefficient MLP ----------------

__global__ void k_stats(const float* __restrict__ h, float* __restrict__ stats) {
    __shared__ float ssum[256], ssq[256];
    int t = threadIdx.x;
    float ls = 0.f, lq = 0.f;
    for (int idx = blockIdx.x * 256 + t; idx < NH; idx += 102400) {
        float v = h[idx];
        ls += v; lq += v * v;
    }
    ssum[t] = ls; ssq[t] = lq;
    __syncthreads();
    if (t < 64) {
        float a = ssum[t] + ssum[t + 64] + ssum[t + 128] + ssum[t + 192];
        atomicAdd(&stats[t], a);
        float q = ssq[t] + ssq[t + 64] + ssq[t + 128] + ssq[t + 192];
        for (int off = 32; off; off >>= 1) q += __shfl_down(q, off, 64);
        if (t == 0) atomicAdd(&stats[64], q);
    }
}

__global__ void k_coeffs(const float* __restrict__ stats,
                         const float* __restrict__ W1, const float* __restrict__ b1,
                         const float* __restrict__ W2, const float* __restrict__ b2,
                         int layer, float* __restrict__ coeffs) {
    __shared__ float ci[68];
    __shared__ float hid[32];
    __shared__ float lg[6];
    int t = threadIdx.x;
    float sf = stats[t];
    float tot = sf;
    for (int off = 1; off < 64; off <<= 1) tot += __shfl_xor(tot, off, 64);
    ci[t] = sf / (float)N_NODES;
    if (t == 0) {
        float sumsq = stats[64];
        float mean = tot / (float)NH;
        float var = (sumsq - (float)NH * mean * mean) / (float)(NH - 1);
        ci[64] = mean;
        ci[65] = sqrtf(fmaxf(var, 0.f));
        ci[66] = (float)N_NODES;
        ci[67] = (float)N_EDGES;
    }
    __syncthreads();
    if (t < 32) {
        float a = b1[layer * 32 + t];
        const float* wr = W1 + (layer * 32 + t) * 68;
        for (int j = 0; j < 68; ++j) a += ci[j] * wr[j];
        hid[t] = fmaxf(a, 0.f);
    }
    __syncthreads();
    if (t < 6) {
        float a = b2[layer * 6 + t];
        const float* wr = W2 + (layer * 6 + t) * 32;
        for (int g = 0; g < 32; ++g) a += hid[g] * wr[g];
        lg[t] = a;
    }
    __syncthreads();
    if (t == 0) {
        float mx = lg[0];
        for (int p = 1; p < 6; ++p) mx = fmaxf(mx, lg[p]);
        float s = 0.f, e[6];
        for (int p = 0; p < 6; ++p) { e[p] = expf(lg[p] - mx); s += e[p]; }
        for (int p = 0; p < 6; ++p) coeffs[p] = e[p] / s;
    }
}

// ---------------- SpMM hop: wave per node, lane = feature, 4 B/edge stream ----------------

__global__ void __launch_bounds__(256) k_spmm(
    const unsigned short* __restrict__ txo, unsigned short* __restrict__ txn,
    const int* __restrict__ row_ptr, const unsigned int* __restrict__ pairs4) {
    int lane = threadIdx.x & 63;
    int wv = __builtin_amdgcn_readfirstlane((int)(blockIdx.x * 4 + (threadIdx.x >> 6)));
    int s = __builtin_amdgcn_readfirstlane(row_ptr[wv]);
    int e = __builtin_amdgcn_readfirstlane(row_ptr[wv + 1]);
    float acc = 0.f;
    int j = s;
    for (; j + 7 < e; j += 8) {
        unsigned p0 = pairs4[j],     p1 = pairs4[j + 1], p2 = pairs4[j + 2], p3 = pairs4[j + 3];
        unsigned p4 = pairs4[j + 4], p5 = pairs4[j + 5], p6 = pairs4[j + 6], p7 = pairs4[j + 7];
        float g0 = bu2f(txo[(p0 >> 16) * 64 + lane]);
        float g1 = bu2f(txo[(p1 >> 16) * 64 + lane]);
        float g2 = bu2f(txo[(p2 >> 16) * 64 + lane]);
        float g3 = bu2f(txo[(p3 >> 16) * 64 + lane]);
        float g4 = bu2f(txo[(p4 >> 16) * 64 + lane]);
        float g5 = bu2f(txo[(p5 >> 16) * 64 + lane]);
        float g6 = bu2f(txo[(p6 >> 16) * 64 + lane]);
        float g7 = bu2f(txo[(p7 >> 16) * 64 + lane]);
        acc += bu2f(p0 & 0xFFFFu) * g0 + bu2f(p1 & 0xFFFFu) * g1 +
               bu2f(p2 & 0xFFFFu) * g2 + bu2f(p3 & 0xFFFFu) * g3;
        acc += bu2f(p4 & 0xFFFFu) * g4 + bu2f(p5 & 0xFFFFu) * g5 +
               bu2f(p6 & 0xFFFFu) * g6 + bu2f(p7 & 0xFFFFu) * g7;
    }
    for (; j < e; ++j) {
        unsigned p = pairs4[j];
        acc += bu2f(p & 0xFFFFu) * bu2f(txo[(p >> 16) * 64 + lane]);
    }
    txn[wv * 64 + lane] = f2bu(acc);
}

// ---------------- fused polynomial combine + layernorm ----------------

__global__ void k_diffln(float* __restrict__ h, unsigned short* __restrict__ h_bf,
                         const unsigned short* __restrict__ t1, const unsigned short* __restrict__ t2,
                         const unsigned short* __restrict__ t3, const unsigned short* __restrict__ t4,
                         const unsigned short* __restrict__ t5,
                         const float* __restrict__ coeffs,
                         const float* __restrict__ sc, const float* __restrict__ bi,
                         int layer, int last, void* __restrict__ outv,
                         const int* __restrict__ flag) {
    int wv = (blockIdx.x * 256 + threadIdx.x) >> 6;
    int lane = threadIdx.x & 63;
    if (wv >= N_NODES) return;
    int o = wv * 64 + lane;
    float c0 = coeffs[0], c1 = coeffs[1], c2 = coeffs[2],
          c3 = coeffs[3], c4 = coeffs[4], c5 = coeffs[5];
    float v = (1.f + c0) * h[o] + c1 * bu2f(t1[o]) + c2 * bu2f(t2[o]) +
              c3 * bu2f(t3[o]) + c4 * bu2f(t4[o]) + c5 * bu2f(t5[o]);
    float m = v;
    for (int off = 1; off < 64; off <<= 1) m += __shfl_xor(m, off, 64);
    m *= (1.f / 64.f);
    float d = v - m;
    float q = d * d;
    for (int off = 1; off < 64; off <<= 1) q += __shfl_xor(q, off, 64);
    float var = q * (1.f / 64.f);
    float y = d / sqrtf(var + 1e-5f) * sc[layer * 64 + lane] + bi[layer * 64 + lane];
    h[o] = y;
    h_bf[o] = f2bu(y);
    if (last) {
        if (*flag) ((float*)outv)[N_EDGES + o] = y;
        else       ((unsigned short*)outv)[N_EDGES + o] = f2bu(y);
    }
}

// ---------------- edge predictor ----------------

__global__ void __launch_bounds__(256) k_uv(const float* __restrict__ h,
                                            const float* __restrict__ W1,
                                            unsigned short* __restrict__ ub,
                                            unsigned short* __restrict__ vb) {
    __shared__ float Wt[128 * 65];
    __shared__ float hs[4 * 64];
    int t = threadIdx.x;
    for (int idx = t; idx < 8192; idx += 256) {
        int f = idx >> 7, j = idx & 127;
        Wt[j * 65 + f] = W1[idx];
    }
    int node0 = blockIdx.x * 4;
    hs[t] = h[node0 * 64 + t];
    __syncthreads();
    int ni = t >> 6, f = t & 63;
    const float* hr = hs + ni * 64;
    float au = 0.f, av = 0.f;
#pragma unroll 8
    for (int j = 0; j < 64; ++j) {
        float xv = hr[j];
        au += Wt[j * 65 + f] * xv;
        av += Wt[(j + 64) * 65 + f] * xv;
    }
    int i = node0 + ni;
    ub[i * 64 + f] = f2bu(au);
    vb[i * 64 + f] = f2bu(av);
}

// MFMA edge predictor: 16 CSR-ordered edges per wave-iteration.
__global__ void __launch_bounds__(256) k_edgepred(
    const unsigned short* __restrict__ ub, const unsigned short* __restrict__ vb,
    const int2* __restrict__ pairs8,
    const float* __restrict__ eb1, const float* __restrict__ eW2,
    const float* __restrict__ eb2, const float* __restrict__ eW3,
    const float* __restrict__ eb3,
    void* __restrict__ outv, const int* __restrict__ flag) {
    int t = threadIdx.x;
    int lane = t & 63;
    int m = lane & 15, q = lane >> 4;
    int f32o = *flag;

    short8 B00, B01, B10, B11;
#pragma unroll
    for (int j = 0; j < 8; ++j) {
        B00[j] = (short)f2bu(eW2[(m) * 64      + q * 8 + j]);
        B01[j] = (short)f2bu(eW2[(m) * 64 + 32 + q * 8 + j]);
        B10[j] = (short)f2bu(eW2[(m + 16) * 64      + q * 8 + j]);
        B11[j] = (short)f2bu(eW2[(m + 16) * 64 + 32 + q * 8 + j]);
    }
    float b1f0[8], b1f1[8];
#pragma unroll
    for (int j = 0; j < 8; ++j) {
        b1f0[j] = eb1[q * 8 + j];
        b1f1[j] = eb1[32 + q * 8 + j];
    }
    float w3a = eW3[m], w3b = eW3[16 + m];
    float b2a = eb2[m], b2b = eb2[16 + m];
    float b3v = eb3[0];

    int gw = blockIdx.x * 4 + (t >> 6);
    const int NW = 1563 * 4;
    for (int tile = gw; tile < N_EDGES / 16; tile += NW) {
        int base = tile << 4;
        int2 pm = pairs8[base + m];
        int col = pm.x & 0xFFFF;
        int row = ((unsigned)pm.x) >> 16;
        int eidv = pm.y;
        const unsigned short* up = ub + row * 64;
        const unsigned short* vp = vb + col * 64;
        uint4 U0 = *(const uint4*)(up + q * 8);
        uint4 U1 = *(const uint4*)(up + 32 + q * 8);
        uint4 V0 = *(const uint4*)(vp + q * 8);
        uint4 V1 = *(const uint4*)(vp + 32 + q * 8);
        short8 A0, A1;
        {
            unsigned uu[4] = {U0.x, U0.y, U0.z, U0.w};
            unsigned vv[4] = {V0.x, V0.y, V0.z, V0.w};
#pragma unroll
            for (int w = 0; w < 4; ++w) {
                float e0 = fmaxf(bu2f(uu[w] & 0xFFFFu) + bu2f(vv[w] & 0xFFFFu) + b1f0[2 * w], 0.f);
                float e1 = fmaxf(bu2f(uu[w] >> 16)     + bu2f(vv[w] >> 16)     + b1f0[2 * w + 1], 0.f);
                A0[2 * w] = (short)f2bu(e0);
                A0[2 * w + 1] = (short)f2bu(e1);
            }
        }
        {
            unsigned uu[4] = {U1.x, U1.y, U1.z, U1.w};
            unsigned vv[4] = {V1.x, V1.y, V1.z, V1.w};
#pragma unroll
            for (int w = 0; w < 4; ++w) {
                float e0 = fmaxf(bu2f(uu[w] & 0xFFFFu) + bu2f(vv[w] & 0xFFFFu) + b1f1[2 * w], 0.f);
                float e1 = fmaxf(bu2f(uu[w] >> 16)     + bu2f(vv[w] >> 16)     + b1f1[2 * w + 1], 0.f);
                A1[2 * w] = (short)f2bu(e0);
                A1[2 * w + 1] = (short)f2bu(e1);
            }
        }
        f32x4 acc0 = {0.f, 0.f, 0.f, 0.f};
        f32x4 acc1 = {0.f, 0.f, 0.f, 0.f};
        acc0 = __builtin_amdgcn_mfma_f32_16x16x32_bf16(A0, B00, acc0, 0, 0, 0);
        acc0 = __builtin_amdgcn_mfma_f32_16x16x32_bf16(A1, B01, acc0, 0, 0, 0);
        acc1 = __builtin_amdgcn_mfma_f32_16x16x32_bf16(A0, B10, acc1, 0, 0, 0);
        acc1 = __builtin_amdgcn_mfma_f32_16x16x32_bf16(A1, B11, acc1, 0, 0, 0);
        float z[4];
#pragma unroll
        for (int rr = 0; rr < 4; ++rr) {
            z[rr] = w3a * fmaxf(acc0[rr] + b2a, 0.f) + w3b * fmaxf(acc1[rr] + b2b, 0.f);
            z[rr] += __shfl_xor(z[rr], 1, 64);
            z[rr] += __shfl_xor(z[rr], 2, 64);
            z[rr] += __shfl_xor(z[rr], 4, 64);
            z[rr] += __shfl_xor(z[rr], 8, 64);
        }
#pragma unroll
        for (int rr = 0; rr < 4; ++rr) {
            int src = (q << 4) + (q << 2) + rr;
            int eidr = __shfl(eidv, src, 64);
            if (m == 0) {
                float p = 1.f / (1.f + __expf(-(z[rr] + b3v)));
                if (f32o) ((float*)outv)[eidr] = p;
                else      ((unsigned short*)outv)[eidr] = f2bu(p);
            }
        }
    }
}

// ---------------- launch ----------------

extern "C" void kernel_launch(void* const* d_in, const int* in_sizes, int n_in,
                              void* d_out, int out_size, void* d_ws, size_t ws_size,
                              hipStream_t stream) {
    (void)in_sizes; (void)n_in; (void)out_size; (void)ws_size;
    const void* x_r   = d_in[0];
    const int*  ei    = (const int*)d_in[1];
    const void* ew_r  = d_in[2];

    char* w = (char*)d_ws;
    float* h            = (float*)w;          w += (size_t)NH * 4;       // 12.8 MB
    unsigned short* hbf = (unsigned short*)w; w += (size_t)NH * 2;       // 6.4
    char* txr           = w;                  w += (size_t)NH * 10;      // 32 (5 bufs)
    unsigned int* pairs4 = (unsigned int*)w;  w += (size_t)N_EDGES * 4;  // 6.4
    int2* pairs8        = (int2*)w;           w += (size_t)N_EDGES * 8;  // 12.8
    int* row_ptr        = (int*)w;            w += 200192;
    float* cWin = (float*)w; w += 2048;
    float* cbin = (float*)w; w += 256;
    float* ccW1 = (float*)w; w += 26112;
    float* ccb1 = (float*)w; w += 384;
    float* ccW2 = (float*)w; w += 2304;
    float* ccb2 = (float*)w; w += 128;
    float* clns = (float*)w; w += 768;
    float* clnb = (float*)w; w += 768;
    float* ceW1 = (float*)w; w += 32768;
    float* ceb1 = (float*)w; w += 256;
    float* ceW2 = (float*)w; w += 8192;
    float* ceb2 = (float*)w; w += 128;
    float* ceW3 = (float*)w; w += 128;
    float* ceb3 = (float*)w; w += 128;
    float* deg  = (float*)w; w += 200192;
    int*   cnt  = (int*)w;   w += 200192;
    char* zero_base = w;
    float* stats = (float*)w; w += 1024;
    size_t zero_bytes = (size_t)(w - zero_base);
    float* coeffs = (float*)w; w += 128;
    int*   flag   = (int*)w;   w += 128;

    // overlays inside the 32 MB txr region (lifetimes disjoint with tx hop buffers):
    float* cew = (float*)txr;                               // [0, 6.4 MB)
    float* cx  = cew + N_EDGES;                             // [6.4, 8.0 MB)
    int*   pcnt = (int*)(txr + (size_t)8 * 1024 * 1024);    // 32*PADN*4 = 7.34 MB
    float* pdeg = (float*)(txr + (size_t)16 * 1024 * 1024); // 7.34 MB
    int*   pref = (int*)(txr + (size_t)24 * 1024 * 1024);   // 32*N_NODES*4 = 6.4 MB
    unsigned short* tx[5];
    for (int k = 0; k < 5; ++k) tx[k] = (unsigned short*)txr + (size_t)k * NH;
    unsigned short* ub = tx[0];   // k_uv runs after last diffln: tx dead
    unsigned short* vb = tx[1];

    hipMemsetAsync(zero_base, 0, zero_bytes, stream);

    k_detect<<<1, 64, 0, stream>>>(ew_r, flag);

    ConvArgs ca;
    const void* srcs[14] = {d_in[3], d_in[4], d_in[5], d_in[6], d_in[7], d_in[8], d_in[9],
                            d_in[10], d_in[11], d_in[12], d_in[13], d_in[14], d_in[15], d_in[16]};
    float* dsts[14] = {cWin, cbin, ccW1, ccb1, ccW2, ccb2, clns,
                       clnb, ceW1, ceb1, ceW2, ceb2, ceW3, ceb3};
    int sizes[14] = {512, 64, 6528, 96, 576, 18, 192, 192, 8192, 64, 2048, 32, 32, 1};
    int c = 0;
    for (int i = 0; i < 14; ++i) { ca.src[i] = srcs[i]; ca.dst[i] = dsts[i]; ca.cum[i] = c; c += sizes[i]; }
    ca.cum[14] = c;
    k_conv<<<(2000000 + c + 255) / 256, 256, 0, stream>>>(x_r, ew_r, cx, cew, ca, flag);

    k_hist<<<NSLICE * NSUB, 256, 0, stream>>>(ei, cew, pcnt, pdeg);
    k_merge<<<196, 256, 0, stream>>>(pcnt, pdeg, cnt, deg, pref);
    k_scan<<<1, 1024, 0, stream>>>(cnt, row_ptr);
    k_place<<<NSLICE * NSUB, 256, 0, stream>>>(ei, cew, deg, row_ptr, pref, pairs4, pairs8);
    k_sort<<<12500, 256, 0, stream>>>(row_ptr, pairs4);
    k_inproj<<<12500, 256, 0, stream>>>(cx, cWin, cbin, h, hbf);

    for (int l = 0; l < NLAYERS; ++l) {
        k_stats<<<400, 256, 0, stream>>>(h, stats + l * 80);
        k_coeffs<<<1, 64, 0, stream>>>(stats + l * 80, ccW1, ccb1, ccW2, ccb2, l,
                                       coeffs + l * 8);
        const unsigned short* src = hbf;
        for (int k = 0; k < 5; ++k) {
            k_spmm<<<12500, 256, 0, stream>>>(src, tx[k], row_ptr, pairs4);
            src = tx[k];
        }
        k_diffln<<<12500, 256, 0, stream>>>(h, hbf, tx[0], tx[1], tx[2], tx[3], tx[4],
                                            coeffs + l * 8, clns, clnb, l,
                                            (l == NLAYERS - 1) ? 1 : 0, d_out, flag);
    }

    k_uv<<<12500, 256, 0, stream>>>(h, ceW1, ub, vb);
    k_edgepred<<<1563, 256, 0, stream>>>(ub, vb, pairs8, ceb1, ceW2, ceb2, ceW3, ceb3,
                                         d_out, flag);
}